// Round 15
// baseline (109.781 us; speedup 1.0000x reference)
//
#include <hip/hip_runtime.h>
#include <hip/hip_bf16.h>

#define EMB_DIM 128
#define LIDX_CAP 1024   // LDS idx staging capacity (segments avg 32)

// Kernel 1: start[n] = lower_bound(segment_ids, n) for n in [0, N]
// 10001 independent binary searches, all latency-overlapped.
__global__ void seg_starts_kernel(const int* __restrict__ seg, int E, int N,
                                  int* __restrict__ start) {
    int n = blockIdx.x * blockDim.x + threadIdx.x;
    if (n > N) return;
    int lo = 0, hi = E;
    while (lo < hi) {
        int mid = (lo + hi) >> 1;
        if (seg[mid] < n) lo = mid + 1; else hi = mid;
    }
    start[n] = lo;
}

// Kernel 2: one 128-thread block per node.
//   group g = t/32 (4 edge-groups, stride 4), lane c = t%32 (float4 = cols 4c..4c+3)
//   8-deep unroll: 8 independent row-loads in flight per thread (rows
//   g, g+4, ..., g+28 — covers a full avg segment of 32 in one shot).
__global__ void seg_mean_kernel(const float* __restrict__ W,
                                const int* __restrict__ idx,
                                const int* __restrict__ start,
                                float* __restrict__ out) {
    int n = blockIdx.x;
    int t = threadIdx.x;          // 0..127
    int g = t >> 5;               // 0..3
    int c = t & 31;               // 0..31
    int s = start[n];
    int e = start[n + 1];
    int cnt = e - s;

    __shared__ int lidx[LIDX_CAP];
    for (int j = t; j < cnt && j < LIDX_CAP; j += 128)
        lidx[j] = idx[s + j];
    __syncthreads();

    const float4* Wv = (const float4*)W;   // row r starts at Wv[r*32]

    float4 a0 = make_float4(0.f,0.f,0.f,0.f);
    float4 a1 = make_float4(0.f,0.f,0.f,0.f);
    float4 a2 = make_float4(0.f,0.f,0.f,0.f);
    float4 a3 = make_float4(0.f,0.f,0.f,0.f);

    int j = g;
    // main: 8 independent row loads per iteration (rows j, j+4, ..., j+28)
    for (; j + 28 < cnt; j += 32) {
        int r0 = lidx[j];
        int r1 = lidx[j + 4];
        int r2 = lidx[j + 8];
        int r3 = lidx[j + 12];
        int r4 = lidx[j + 16];
        int r5 = lidx[j + 20];
        int r6 = lidx[j + 24];
        int r7 = lidx[j + 28];
        float4 v0 = Wv[r0 * 32 + c];
        float4 v1 = Wv[r1 * 32 + c];
        float4 v2 = Wv[r2 * 32 + c];
        float4 v3 = Wv[r3 * 32 + c];
        float4 v4 = Wv[r4 * 32 + c];
        float4 v5 = Wv[r5 * 32 + c];
        float4 v6 = Wv[r6 * 32 + c];
        float4 v7 = Wv[r7 * 32 + c];
        a0.x += v0.x; a0.y += v0.y; a0.z += v0.z; a0.w += v0.w;
        a1.x += v1.x; a1.y += v1.y; a1.z += v1.z; a1.w += v1.w;
        a2.x += v2.x; a2.y += v2.y; a2.z += v2.z; a2.w += v2.w;
        a3.x += v3.x; a3.y += v3.y; a3.z += v3.z; a3.w += v3.w;
        a0.x += v4.x; a0.y += v4.y; a0.z += v4.z; a0.w += v4.w;
        a1.x += v5.x; a1.y += v5.y; a1.z += v5.z; a1.w += v5.w;
        a2.x += v6.x; a2.y += v6.y; a2.z += v6.z; a2.w += v6.w;
        a3.x += v7.x; a3.y += v7.y; a3.z += v7.z; a3.w += v7.w;
    }
    // tail: stride-4 single loads
    for (; j < cnt; j += 4) {
        int r = (j < LIDX_CAP) ? lidx[j] : idx[s + j];
        float4 v = Wv[r * 32 + c];
        a0.x += v.x; a0.y += v.y; a0.z += v.z; a0.w += v.w;
    }

    a0.x += a1.x + a2.x + a3.x;
    a0.y += a1.y + a2.y + a3.y;
    a0.z += a1.z + a2.z + a3.z;
    a0.w += a1.w + a2.w + a3.w;

    __shared__ float4 red[4][32];
    red[g][c] = a0;
    __syncthreads();

    if (g == 0) {
        float4 a = red[0][c];
        #pragma unroll
        for (int gg = 1; gg < 4; ++gg) {
            float4 v = red[gg][c];
            a.x += v.x; a.y += v.y; a.z += v.z; a.w += v.w;
        }
        float inv = 1.0f / fmaxf((float)cnt, 1.0f);
        float4 o = make_float4(a.x * inv, a.y * inv, a.z * inv, a.w * inv);
        ((float4*)(out + (long long)n * EMB_DIM))[c] = o;
    }
}

extern "C" void kernel_launch(void* const* d_in, const int* in_sizes, int n_in,
                              void* d_out, int out_size, void* d_ws, size_t ws_size,
                              hipStream_t stream) {
    const float* weight      = (const float*)d_in[0];
    const int*   neigh_idx   = (const int*)d_in[1];
    const int*   segment_ids = (const int*)d_in[2];
    int N = out_size / EMB_DIM;       // 10000
    int E = in_sizes[1];              // 320000

    int* start = (int*)d_ws;          // (N+1) ints

    {
        int threads = 256;
        int blocks = (N + 1 + threads - 1) / threads;
        seg_starts_kernel<<<blocks, threads, 0, stream>>>(segment_ids, E, N, start);
    }
    seg_mean_kernel<<<N, 128, 0, stream>>>(weight, neigh_idx, start, (float*)d_out);
}